// Round 11
// baseline (828.555 us; speedup 1.0000x reference)
//
#include <hip/hip_runtime.h>
#include <stdint.h>

typedef unsigned short u16;
typedef unsigned int   u32;

typedef __attribute__((ext_vector_type(8))) short bf16x8;
typedef __attribute__((ext_vector_type(4))) float f32x4;

#define NNODES 8000
#define BSZ    32
#define UNITS  64
#define EDG    64000
#define ROWCH  288           /* 16B chunks per matrix block: 9 slices * 32 b */
#define NODECH 1440          /* chunks per node row: 5 matrices * 288 */
#define NODEU16 11520        /* u16 per node row */
#define KLIN   384           /* 12 steps * 32: per-matrix k=72 (9 slices), 5*72=360 real+pad, 24 tail */
#define NSTEPS 12
#define HXROW  512000
#define INROW  16000

__device__ __forceinline__ u32 f2bf(float f){
    u32 u = __float_as_uint(f);
    return (u + 0x7FFFu + ((u >> 16) & 1u)) >> 16;   // RNE
}
__device__ __forceinline__ float bfu(u16 s){ return __uint_as_float(((u32)s) << 16); }
__device__ __forceinline__ float lo16(u32 u){ return __uint_as_float(u << 16); }
__device__ __forceinline__ float hi16(u32 u){ return __uint_as_float(u & 0xFFFF0000u); }
__device__ __forceinline__ float sigm(float x){ return 1.f / (1.f + __expf(-x)); }

#define GLDS(gsrc, ldst) \
    __builtin_amdgcn_global_load_lds((const __attribute__((address_space(1))) void*)(gsrc), \
                                     (__attribute__((address_space(3))) void*)(ldst), 16, 0, 0)

// ---------------- CSR build for support 0 ----------------
__global__ void hist_k(const int* __restrict__ rows, int* __restrict__ counts){
    int e = blockIdx.x * 256 + threadIdx.x;
    if (e < EDG) atomicAdd(&counts[rows[e]], 1);
}

__global__ __launch_bounds__(256) void scan_k(const int* __restrict__ counts,
                                              int* __restrict__ row_ptr,
                                              int* __restrict__ cursor){
    __shared__ int part[256];
    int t = threadIdx.x;
    int s = 0;
    for (int i = 0; i < 32; ++i){ int r = t*32 + i; if (r < NNODES) s += counts[r]; }
    part[t] = s;
    __syncthreads();
    if (t == 0){
        int run = 0;
        for (int i = 0; i < 256; ++i){ int v = part[i]; part[i] = run; run += v; }
    }
    __syncthreads();
    int run = part[t];
    for (int i = 0; i < 32; ++i){
        int r = t*32 + i;
        if (r < NNODES){ row_ptr[r] = run; cursor[r] = run; run += counts[r]; }
    }
    if (t == 255) row_ptr[NNODES] = run;
}

__global__ void scatter_k(const int* __restrict__ rows, const int* __restrict__ cols,
                          const float* __restrict__ vals, int* __restrict__ cursor,
                          int* __restrict__ cs, float* __restrict__ vs){
    int e = blockIdx.x * 256 + threadIdx.x;
    if (e < EDG){
        int r = rows[e];
        int slot = atomicAdd(&cursor[r], 1);
        cs[slot] = cols[e];
        vs[slot] = vals[e];
    }
}

// ---------------- W pre-permute, Chebyshev folded, FEATURE-REORDERED ----------------
// Feature order in X rows: [state 0..63 | inputs 64,65 | pad 66..71].
// Original W row index = old_fp*5 + m with old_fp: 0,1=inputs, 2..65=state.
// new fp<64 -> old_fp = fp+2 ; fp 64,65 -> old_fp = fp-64.
// Fold: W0'=W0-W2-W4, W2'=2W2, W4'=2W4.  WtS[((st*4+q)*C + col)*8 + j].
__global__ void prep_w_k(const float* __restrict__ W_ru, const float* __restrict__ W_c,
                         u16* __restrict__ Wt_ru, u16* __restrict__ Wt_c){
    int id = blockIdx.x * 256 + threadIdx.x;
    if (id < 128*KLIN){
        int j = id & 7;
        int cell = id >> 3;
        int col = cell & 127;
        int sq = cell >> 7;                  // st*4+q
        int kl = sq*8 + j;
        int m = kl / 72, fp = kl - m*72;
        u16 v = 0;
        if (m < 5 && fp < 66){
            int of = (fp < 64) ? (fp + 2) : (fp - 64);
            float w;
            if (m == 0)      w = W_ru[(of*5 + 0)*128 + col] - W_ru[(of*5 + 2)*128 + col] - W_ru[(of*5 + 4)*128 + col];
            else if (m == 2) w = 2.f * W_ru[(of*5 + 2)*128 + col];
            else if (m == 4) w = 2.f * W_ru[(of*5 + 4)*128 + col];
            else             w = W_ru[(of*5 + m)*128 + col];
            v = (u16)f2bf(w);
        }
        Wt_ru[id] = v;
    }
    int id2 = id - 128*KLIN;
    if (id2 >= 0 && id2 < 64*KLIN){
        int j = id2 & 7;
        int cell = id2 >> 3;
        int col = cell & 63;
        int sq = cell >> 6;
        int kl = sq*8 + j;
        int m = kl / 72, fp = kl - m*72;
        u16 v = 0;
        if (m < 5 && fp < 66){
            int of = (fp < 64) ? (fp + 2) : (fp - 64);
            float w;
            if (m == 0)      w = W_c[(of*5 + 0)*64 + col] - W_c[(of*5 + 2)*64 + col] - W_c[(of*5 + 4)*64 + col];
            else if (m == 2) w = 2.f * W_c[(of*5 + 2)*64 + col];
            else if (m == 4) w = 2.f * W_c[(of*5 + 4)*64 + col];
            else             w = W_c[(of*5 + m)*64 + col];
            v = (u16)f2bf(w);
        }
        Wt_c[id2] = v;
    }
}

// ---------------- build x0 (matrix 0), fp-major chunks, [state|inputs|pad] order ----------------
__global__ __launch_bounds__(256) void build_x0_k(const float* __restrict__ inputs,
                                                  const float* __restrict__ hx,
                                                  u16* __restrict__ Xu){
    __shared__ float sl[32*72];
    int n = blockIdx.x, t = threadIdx.x;
    #pragma unroll
    for (int i = 0; i < 8; ++i){
        int idx = t + i*256;                // 2048 hx elems -> fp 0..63
        int b = idx >> 6, f = idx & 63;
        sl[b*72 + f] = hx[b*HXROW + n*64 + f];
    }
    if (t < 64){
        int b = t >> 1, d = t & 1;
        sl[b*72 + 64 + d] = inputs[b*INROW + n*2 + d];
    }
    if (t < 192){
        int b = t / 6, k = t - b*6;
        sl[b*72 + 66 + k] = 0.f;
    }
    __syncthreads();
    #pragma unroll
    for (int i = 0; i < 2; ++i){
        int j = t + i*256;
        if (j < ROWCH){
            int b = j & 31, s = j >> 5;
            const float* p = &sl[b*72 + s*8];
            uint4 o;
            o.x = f2bf(p[0]) | (f2bf(p[1]) << 16);
            o.y = f2bf(p[2]) | (f2bf(p[3]) << 16);
            o.z = f2bf(p[4]) | (f2bf(p[5]) << 16);
            o.w = f2bf(p[6]) | (f2bf(p[7]) << 16);
            ((uint4*)Xu)[(size_t)n*NODECH + j] = o;
        }
    }
}

__device__ __forceinline__ void acc8(float* a, uint4 q, float v){
    a[0] += v*lo16(q.x); a[1] += v*hi16(q.x);
    a[2] += v*lo16(q.y); a[3] += v*hi16(q.y);
    a[4] += v*lo16(q.z); a[5] += v*hi16(q.z);
    a[6] += v*lo16(q.w); a[7] += v*hi16(q.w);
}
__device__ __forceinline__ uint4 pack8(const float* a){
    uint4 o;
    o.x = f2bf(a[0]) | (f2bf(a[1]) << 16);
    o.y = f2bf(a[2]) | (f2bf(a[3]) << 16);
    o.z = f2bf(a[4]) | (f2bf(a[5]) << 16);
    o.w = f2bf(a[6]) | (f2bf(a[7]) << 16);
    return o;
}

// ---------------- diffusion level 1: m1 = S0*m0, m3 = S1*m0 ----------------
// 2 nodes/block, 576 thr = 9 FULL waves. Slice-8 threads (tt>=256): chunk is
// 4B real (inputs fp64,65) + 12B zero pad -> gather 4B only (-8.3% bytes);
// stores stay 16B with zeroed pad so GEMM never reads uninitialized bits.
__global__ __launch_bounds__(576) void diff1_k(u16* __restrict__ Xu,
                                               const int* __restrict__ rp,
                                               const int* __restrict__ c0, const float* __restrict__ v0,
                                               const int* __restrict__ c1, const float* __restrict__ v1){
    const int t = threadIdx.x;
    const int half = (t >= 288) ? 1 : 0;
    const int tt = t - half*288;
    const int n = blockIdx.x*2 + half;
    if (tt < 256){
        const uint4* xb = (const uint4*)Xu;
        float a[8] = {0,0,0,0,0,0,0,0};
        float d[8] = {0,0,0,0,0,0,0,0};
        {
            uint4 q[8]; float vv[8];
            #pragma unroll
            for (int i = 0; i < 8; ++i){
                int c = c1[n*8 + i]; vv[i] = v1[n*8 + i];
                q[i] = xb[(size_t)c*NODECH + tt];
            }
            #pragma unroll
            for (int i = 0; i < 8; ++i) acc8(d, q[i], vv[i]);
        }
        int e = rp[n], end = rp[n+1];
        for (; e + 8 <= end; e += 8){
            uint4 q[8]; float vv[8];
            #pragma unroll
            for (int i = 0; i < 8; ++i){
                int c = c0[e+i]; vv[i] = v0[e+i];
                q[i] = xb[(size_t)c*NODECH + tt];
            }
            #pragma unroll
            for (int i = 0; i < 8; ++i) acc8(a, q[i], vv[i]);
        }
        for (; e < end; ++e){
            int c = c0[e]; float v = v0[e];
            acc8(a, xb[(size_t)c*NODECH + tt], v);
        }
        ((uint4*)Xu)[(size_t)n*NODECH + 1*ROWCH + tt] = pack8(a);
        ((uint4*)Xu)[(size_t)n*NODECH + 3*ROWCH + tt] = pack8(d);
    } else {
        const u32* xb = (const u32*)Xu;
        float a0 = 0.f, a1 = 0.f, d0 = 0.f, d1 = 0.f;
        {
            u32 q[8]; float vv[8];
            #pragma unroll
            for (int i = 0; i < 8; ++i){
                int c = c1[n*8 + i]; vv[i] = v1[n*8 + i];
                q[i] = xb[((size_t)c*NODECH + tt)*4];
            }
            #pragma unroll
            for (int i = 0; i < 8; ++i){ d0 += vv[i]*lo16(q[i]); d1 += vv[i]*hi16(q[i]); }
        }
        int e = rp[n], end = rp[n+1];
        for (; e + 8 <= end; e += 8){
            u32 q[8]; float vv[8];
            #pragma unroll
            for (int i = 0; i < 8; ++i){
                int c = c0[e+i]; vv[i] = v0[e+i];
                q[i] = xb[((size_t)c*NODECH + tt)*4];
            }
            #pragma unroll
            for (int i = 0; i < 8; ++i){ a0 += vv[i]*lo16(q[i]); a1 += vv[i]*hi16(q[i]); }
        }
        for (; e < end; ++e){
            int c = c0[e]; float v = v0[e];
            u32 qv = xb[((size_t)c*NODECH + tt)*4];
            a0 += v*lo16(qv); a1 += v*hi16(qv);
        }
        uint4 o1; o1.x = f2bf(a0) | (f2bf(a1) << 16); o1.y = 0; o1.z = 0; o1.w = 0;
        uint4 o3; o3.x = f2bf(d0) | (f2bf(d1) << 16); o3.y = 0; o3.z = 0; o3.w = 0;
        ((uint4*)Xu)[(size_t)n*NODECH + 1*ROWCH + tt] = o1;
        ((uint4*)Xu)[(size_t)n*NODECH + 3*ROWCH + tt] = o3;
    }
}

// ---------------- diffusion level 2 (fold in W): m2 = S0*m1, m4 = S1*m3 ----------------
__global__ __launch_bounds__(576) void diff2_k(u16* __restrict__ Xu,
                                               const int* __restrict__ rp,
                                               const int* __restrict__ c0, const float* __restrict__ v0,
                                               const int* __restrict__ c1, const float* __restrict__ v1){
    const int t = threadIdx.x;
    const int half = (t >= 288) ? 1 : 0;
    const int tt = t - half*288;
    const int n = blockIdx.x*2 + half;
    if (tt < 256){
        const uint4* xb = (const uint4*)Xu;
        float a[8] = {0,0,0,0,0,0,0,0};
        float d[8] = {0,0,0,0,0,0,0,0};
        {
            uint4 q[8]; float vv[8];
            #pragma unroll
            for (int i = 0; i < 8; ++i){
                int c = c1[n*8 + i]; vv[i] = v1[n*8 + i];
                q[i] = xb[(size_t)c*NODECH + 3*ROWCH + tt];    // gather m=3
            }
            #pragma unroll
            for (int i = 0; i < 8; ++i) acc8(d, q[i], vv[i]);
        }
        int e = rp[n], end = rp[n+1];
        for (; e + 8 <= end; e += 8){
            uint4 q[8]; float vv[8];
            #pragma unroll
            for (int i = 0; i < 8; ++i){
                int c = c0[e+i]; vv[i] = v0[e+i];
                q[i] = xb[(size_t)c*NODECH + 1*ROWCH + tt];    // gather m=1
            }
            #pragma unroll
            for (int i = 0; i < 8; ++i) acc8(a, q[i], vv[i]);
        }
        for (; e < end; ++e){
            int c = c0[e]; float v = v0[e];
            acc8(a, xb[(size_t)c*NODECH + 1*ROWCH + tt], v);
        }
        ((uint4*)Xu)[(size_t)n*NODECH + 2*ROWCH + tt] = pack8(a);
        ((uint4*)Xu)[(size_t)n*NODECH + 4*ROWCH + tt] = pack8(d);
    } else {
        const u32* xb = (const u32*)Xu;
        float a0 = 0.f, a1 = 0.f, d0 = 0.f, d1 = 0.f;
        {
            u32 q[8]; float vv[8];
            #pragma unroll
            for (int i = 0; i < 8; ++i){
                int c = c1[n*8 + i]; vv[i] = v1[n*8 + i];
                q[i] = xb[((size_t)c*NODECH + 3*ROWCH + tt)*4];
            }
            #pragma unroll
            for (int i = 0; i < 8; ++i){ d0 += vv[i]*lo16(q[i]); d1 += vv[i]*hi16(q[i]); }
        }
        int e = rp[n], end = rp[n+1];
        for (; e + 8 <= end; e += 8){
            u32 q[8]; float vv[8];
            #pragma unroll
            for (int i = 0; i < 8; ++i){
                int c = c0[e+i]; vv[i] = v0[e+i];
                q[i] = xb[((size_t)c*NODECH + 1*ROWCH + tt)*4];
            }
            #pragma unroll
            for (int i = 0; i < 8; ++i){ a0 += vv[i]*lo16(q[i]); a1 += vv[i]*hi16(q[i]); }
        }
        for (; e < end; ++e){
            int c = c0[e]; float v = v0[e];
            u32 qv = xb[((size_t)c*NODECH + 1*ROWCH + tt)*4];
            a0 += v*lo16(qv); a1 += v*hi16(qv);
        }
        uint4 o2; o2.x = f2bf(a0) | (f2bf(a1) << 16); o2.y = 0; o2.z = 0; o2.w = 0;
        uint4 o4; o4.x = f2bf(d0) | (f2bf(d1) << 16); o4.y = 0; o4.z = 0; o4.w = 0;
        ((uint4*)Xu)[(size_t)n*NODECH + 2*ROWCH + tt] = o2;
        ((uint4*)Xu)[(size_t)n*NODECH + 4*ROWCH + tt] = o4;
    }
}

// ---------------- GEMM1: sigmoid(Xc@W_ru + b_ru); U out; X0.state <- r*hx ----------------
// SWAPPED OPERANDS: acc[mt][nt] = mfma(W_frag, X_frag, acc) -> D[wcol][b].
__global__ __launch_bounds__(1024) void gemm_ru_k(
        const u16* Xu,
        const u16* __restrict__ WtS,       // [(st*4+q)*128+col][8]
        const float* __restrict__ b_ru,
        u16* __restrict__ U, u16* X0st){
    __shared__ u16 Bs[24576];              // 48 KB = 6 steps
    __shared__ float biasL[128];
    const int t = threadIdx.x;
    const int lane = t & 63, w = t >> 6;
    const int node = blockIdx.x*16 + w;
    const int cIn = lane & 15, q = lane >> 4;
    const size_t noff = (size_t)node * NODEU16;
    const u16* Xn = Xu + noff;

    f32x4 acc[8][2];
    const f32x4 z4 = {0.f,0.f,0.f,0.f};
    #pragma unroll
    for (int mt = 0; mt < 8; ++mt)
        #pragma unroll
        for (int nt = 0; nt < 2; ++nt) acc[mt][nt] = z4;

    if (t < 128) biasL[t] = b_ru[t];
    #pragma unroll
    for (int i = 0; i < 3; ++i)
        GLDS(WtS + (size_t)(i*1024 + t)*8, &Bs[(i*1024 + t)*8]);
    __syncthreads();

    #pragma unroll
    for (int h = 0; h < 2; ++h){
        if (h == 1){
            __syncthreads();
            #pragma unroll
            for (int i = 0; i < 3; ++i)
                GLDS(WtS + (size_t)(3072 + i*1024 + t)*8, &Bs[(i*1024 + t)*8]);
            __syncthreads();
        }
        #pragma unroll
        for (int ls = 0; ls < 6; ++ls){
            const int st = h*6 + ls;
            bf16x8 A0 = *(const bf16x8*)&Xn[(size_t)((st*4 + q)*32 + cIn)*8];
            bf16x8 A1 = *(const bf16x8*)&Xn[(size_t)((st*4 + q)*32 + 16 + cIn)*8];
            bf16x8 cb[8];
            #pragma unroll
            for (int mt = 0; mt < 8; ++mt)
                cb[mt] = *(const bf16x8*)&Bs[((ls*4 + q)*128 + mt*16 + cIn)*8];
            #pragma unroll
            for (int mt = 0; mt < 8; ++mt){
                acc[mt][0] = __builtin_amdgcn_mfma_f32_16x16x32_bf16(cb[mt], A0, acc[mt][0], 0,0,0);
                acc[mt][1] = __builtin_amdgcn_mfma_f32_16x16x32_bf16(cb[mt], A1, acc[mt][1], 0,0,0);
            }
        }
    }

    // epilogue: lane holds wcol = mt*16 + q*4 + i, b = nt*16 + cIn
    #pragma unroll
    for (int mt = 0; mt < 8; ++mt){
        const int wc0 = mt*16 + q*4;
        f32x4 b4 = *(const f32x4*)&biasL[wc0];
        #pragma unroll
        for (int nt = 0; nt < 2; ++nt){
            const int b = nt*16 + cIn;
            f32x4 d = acc[mt][nt];
            if (mt < 4){
                size_t base = noff + (size_t)((wc0 >> 3)*32 + b)*8 + (wc0 & 7);
                uint2 hv = *(uint2*)&X0st[base];
                float r0 = sigm(d[0] + b4.x), r1 = sigm(d[1] + b4.y);
                float r2 = sigm(d[2] + b4.z), r3 = sigm(d[3] + b4.w);
                uint2 o;
                o.x = f2bf(r0*lo16(hv.x)) | (f2bf(r1*hi16(hv.x)) << 16);
                o.y = f2bf(r2*lo16(hv.y)) | (f2bf(r3*hi16(hv.y)) << 16);
                *(uint2*)&X0st[base] = o;
            } else {
                float u0 = sigm(d[0] + b4.x), u1 = sigm(d[1] + b4.y);
                float u2 = sigm(d[2] + b4.z), u3 = sigm(d[3] + b4.w);
                uint2 o;
                o.x = f2bf(u0) | (f2bf(u1) << 16);
                o.y = f2bf(u2) | (f2bf(u3) << 16);
                *(uint2*)&U[(size_t)node*2048 + b*64 + (wc0 - 64)] = o;   // U[b][col]
            }
        }
    }
}

// ---------------- GEMM2: c = tanh(Xc@W_c + b_c); out = u*hx + (1-u)*c ----------------
__global__ __launch_bounds__(1024) void gemm_c_k(
        const u16* __restrict__ Xu,
        const u16* __restrict__ WtS,       // [(st*4+q)*64+col][8]
        const float* __restrict__ b_c, const float* __restrict__ hx,
        const u16* __restrict__ U, float* __restrict__ out){
    __shared__ u16 Bs[24576];              // 48 KB = all 12 steps
    __shared__ float biasL[64];
    const int t = threadIdx.x;
    const int lane = t & 63, w = t >> 6;
    const int node = blockIdx.x*16 + w;
    const int cIn = lane & 15, q = lane >> 4;
    const size_t noff = (size_t)node * NODEU16;
    const u16* Xn = Xu + noff;

    f32x4 acc[4][2];
    const f32x4 z4 = {0.f,0.f,0.f,0.f};
    #pragma unroll
    for (int mt = 0; mt < 4; ++mt)
        #pragma unroll
        for (int nt = 0; nt < 2; ++nt) acc[mt][nt] = z4;

    if (t < 64) biasL[t] = b_c[t];
    #pragma unroll
    for (int i = 0; i < 3; ++i)
        GLDS(WtS + (size_t)(i*1024 + t)*8, &Bs[(i*1024 + t)*8]);
    __syncthreads();

    #pragma unroll
    for (int st = 0; st < NSTEPS; ++st){
        bf16x8 A0 = *(const bf16x8*)&Xn[(size_t)((st*4 + q)*32 + cIn)*8];
        bf16x8 A1 = *(const bf16x8*)&Xn[(size_t)((st*4 + q)*32 + 16 + cIn)*8];
        bf16x8 cb[4];
        #pragma unroll
        for (int mt = 0; mt < 4; ++mt)
            cb[mt] = *(const bf16x8*)&Bs[((st*4 + q)*64 + mt*16 + cIn)*8];
        #pragma unroll
        for (int mt = 0; mt < 4; ++mt){
            acc[mt][0] = __builtin_amdgcn_mfma_f32_16x16x32_bf16(cb[mt], A0, acc[mt][0], 0,0,0);
            acc[mt][1] = __builtin_amdgcn_mfma_f32_16x16x32_bf16(cb[mt], A1, acc[mt][1], 0,0,0);
        }
    }

    #pragma unroll
    for (int mt = 0; mt < 4; ++mt){
        const int wc0 = mt*16 + q*4;
        f32x4 b4 = *(const f32x4*)&biasL[wc0];
        #pragma unroll
        for (int nt = 0; nt < 2; ++nt){
            const int b = nt*16 + cIn;
            f32x4 d = acc[mt][nt];
            uint2 up = *(const uint2*)&U[(size_t)node*2048 + b*64 + wc0];   // U[b][col]
            float u0 = lo16(up.x), u1 = hi16(up.x), u2 = lo16(up.y), u3 = hi16(up.y);
            const size_t gi = (size_t)b*HXROW + node*64 + wc0;
            f32x4 h4 = *(const f32x4*)&hx[gi];
            f32x4 o;
            o.x = u0*h4.x + (1.f - u0)*tanhf(d[0] + b4.x);
            o.y = u1*h4.y + (1.f - u1)*tanhf(d[1] + b4.y);
            o.z = u2*h4.z + (1.f - u2)*tanhf(d[2] + b4.z);
            o.w = u3*h4.w + (1.f - u3)*tanhf(d[3] + b4.w);
            *(f32x4*)&out[gi] = o;
        }
    }
}

// ---------------- launch ----------------
extern "C" void kernel_launch(void* const* d_in, const int* in_sizes, int n_in,
                              void* d_out, int out_size, void* d_ws, size_t ws_size,
                              hipStream_t stream){
    const float* inputs = (const float*)d_in[0];
    const float* hx     = (const float*)d_in[1];
    const float* W_ru   = (const float*)d_in[2];
    const float* b_ru   = (const float*)d_in[3];
    const float* W_c    = (const float*)d_in[4];
    const float* b_c    = (const float*)d_in[5];
    const int*   s0r    = (const int*)d_in[6];
    const int*   s0c    = (const int*)d_in[7];
    const float* s0v    = (const float*)d_in[8];
    const int*   s1c    = (const int*)d_in[10];
    const float* s1v    = (const float*)d_in[11];
    float* out = (float*)d_out;

    char* ws = (char*)d_ws;
    size_t off = 0;
    auto alloc = [&](size_t bytes) -> char* {
        char* p = ws + off;
        off += (bytes + 255) & ~(size_t)255;
        return p;
    };
    const size_t XU_BYTES = (size_t)NNODES * NODEU16 * 2;
    u16* Xu   = (u16*)alloc(XU_BYTES + 4096);      // +guard for k-tail overread of last node
    u16* U    = (u16*)alloc((size_t)NNODES*2048*2);
    u16* WtRU = (u16*)alloc((size_t)128*KLIN*2);   // 12 steps * 4096 u16
    u16* WtC  = (u16*)alloc((size_t)64*KLIN*2);    // 12 steps * 2048 u16
    int* counts  = (int*)alloc((size_t)NNODES*4);
    int* row_ptr = (int*)alloc((size_t)(NNODES+1)*4);
    int* cursor  = (int*)alloc((size_t)NNODES*4);
    int*   cols_s = (int*)alloc((size_t)EDG*4);
    float* vals_s = (float*)alloc((size_t)EDG*4);
    (void)ws_size; (void)in_sizes; (void)n_in; (void)out_size;

    // CSR build for support 0 + zero the tail guard
    hipMemsetAsync(counts, 0, (size_t)NNODES*4, stream);
    hipMemsetAsync((char*)Xu + XU_BYTES, 0, 4096, stream);
    hist_k<<<250, 256, 0, stream>>>(s0r, counts);
    scan_k<<<1, 256, 0, stream>>>(counts, row_ptr, cursor);
    scatter_k<<<250, 256, 0, stream>>>(s0r, s0c, s0v, cursor, cols_s, vals_s);

    prep_w_k<<<288, 256, 0, stream>>>(W_ru, W_c, WtRU, WtC);
    build_x0_k<<<NNODES, 256, 0, stream>>>(inputs, hx, Xu);

    // gconv 1 diffusion (2 nodes/block, full waves, 4B slice-8 gathers)
    diff1_k<<<NNODES/2, 576, 0, stream>>>(Xu, row_ptr, cols_s, vals_s, s1c, s1v);
    diff2_k<<<NNODES/2, 576, 0, stream>>>(Xu, row_ptr, cols_s, vals_s, s1c, s1v);

    // GEMM1 + sigmoid; writes U and X0.state = r*hx
    gemm_ru_k<<<NNODES/16, 1024, 0, stream>>>(Xu, WtRU, b_ru, U, Xu);

    // gconv 2 diffusion (matrix 0 now holds [r*hx | inputs])
    diff1_k<<<NNODES/2, 576, 0, stream>>>(Xu, row_ptr, cols_s, vals_s, s1c, s1v);
    diff2_k<<<NNODES/2, 576, 0, stream>>>(Xu, row_ptr, cols_s, vals_s, s1c, s1v);

    // GEMM2 + tanh + final gate
    gemm_c_k<<<NNODES/16, 1024, 0, stream>>>(Xu, WtC, b_c, hx, U, out);
}

// Round 12
// 650.192 us; speedup vs baseline: 1.2743x; 1.2743x over previous
//
#include <hip/hip_runtime.h>
#include <stdint.h>

typedef unsigned short u16;
typedef unsigned int   u32;

typedef __attribute__((ext_vector_type(8))) short bf16x8;
typedef __attribute__((ext_vector_type(4))) float f32x4;

#define NNODES 8000
#define BSZ    32
#define UNITS  64
#define EDG    64000
#define ROWCH  288           /* 16B chunks per matrix block: 9 slices * 32 b */
#define NODECH 1440          /* chunks per node row: 5 matrices * 288 */
#define NODEU16 11520        /* u16 per node row */
#define KLIN   384           /* 12 steps * 32: per-matrix k=72 (9 slices), 5*72=360 real+pad, 24 tail */
#define NSTEPS 12
#define HXROW  512000
#define INROW  16000

__device__ __forceinline__ u32 f2bf(float f){
    u32 u = __float_as_uint(f);
    return (u + 0x7FFFu + ((u >> 16) & 1u)) >> 16;   // RNE
}
__device__ __forceinline__ float bfu(u16 s){ return __uint_as_float(((u32)s) << 16); }
__device__ __forceinline__ float lo16(u32 u){ return __uint_as_float(u << 16); }
__device__ __forceinline__ float hi16(u32 u){ return __uint_as_float(u & 0xFFFF0000u); }
__device__ __forceinline__ float sigm(float x){ return 1.f / (1.f + __expf(-x)); }

#define GLDS(gsrc, ldst) \
    __builtin_amdgcn_global_load_lds((const __attribute__((address_space(1))) void*)(gsrc), \
                                     (__attribute__((address_space(3))) void*)(ldst), 16, 0, 0)

// ---------------- CSR build for support 0 ----------------
__global__ void hist_k(const int* __restrict__ rows, int* __restrict__ counts){
    int e = blockIdx.x * 256 + threadIdx.x;
    if (e < EDG) atomicAdd(&counts[rows[e]], 1);
}

__global__ __launch_bounds__(256) void scan_k(const int* __restrict__ counts,
                                              int* __restrict__ row_ptr,
                                              int* __restrict__ cursor){
    __shared__ int part[256];
    int t = threadIdx.x;
    int s = 0;
    for (int i = 0; i < 32; ++i){ int r = t*32 + i; if (r < NNODES) s += counts[r]; }
    part[t] = s;
    __syncthreads();
    if (t == 0){
        int run = 0;
        for (int i = 0; i < 256; ++i){ int v = part[i]; part[i] = run; run += v; }
    }
    __syncthreads();
    int run = part[t];
    for (int i = 0; i < 32; ++i){
        int r = t*32 + i;
        if (r < NNODES){ row_ptr[r] = run; cursor[r] = run; run += counts[r]; }
    }
    if (t == 255) row_ptr[NNODES] = run;
}

__global__ void scatter_k(const int* __restrict__ rows, const int* __restrict__ cols,
                          const float* __restrict__ vals, int* __restrict__ cursor,
                          int* __restrict__ cs, float* __restrict__ vs){
    int e = blockIdx.x * 256 + threadIdx.x;
    if (e < EDG){
        int r = rows[e];
        int slot = atomicAdd(&cursor[r], 1);
        cs[slot] = cols[e];
        vs[slot] = vals[e];
    }
}

// ---------------- W pre-permute, Chebyshev folded, FEATURE-REORDERED ----------------
// Feature order in X rows: [state 0..63 | inputs 64,65 | pad 66..71].
// Original W row index = old_fp*5 + m with old_fp: 0,1=inputs, 2..65=state.
// new fp<64 -> old_fp = fp+2 ; fp 64,65 -> old_fp = fp-64.
// Fold: W0'=W0-W2-W4, W2'=2W2, W4'=2W4.  WtS[((st*4+q)*C + col)*8 + j].
__global__ void prep_w_k(const float* __restrict__ W_ru, const float* __restrict__ W_c,
                         u16* __restrict__ Wt_ru, u16* __restrict__ Wt_c){
    int id = blockIdx.x * 256 + threadIdx.x;
    if (id < 128*KLIN){
        int j = id & 7;
        int cell = id >> 3;
        int col = cell & 127;
        int sq = cell >> 7;                  // st*4+q
        int kl = sq*8 + j;
        int m = kl / 72, fp = kl - m*72;
        u16 v = 0;
        if (m < 5 && fp < 66){
            int of = (fp < 64) ? (fp + 2) : (fp - 64);
            float w;
            if (m == 0)      w = W_ru[(of*5 + 0)*128 + col] - W_ru[(of*5 + 2)*128 + col] - W_ru[(of*5 + 4)*128 + col];
            else if (m == 2) w = 2.f * W_ru[(of*5 + 2)*128 + col];
            else if (m == 4) w = 2.f * W_ru[(of*5 + 4)*128 + col];
            else             w = W_ru[(of*5 + m)*128 + col];
            v = (u16)f2bf(w);
        }
        Wt_ru[id] = v;
    }
    int id2 = id - 128*KLIN;
    if (id2 >= 0 && id2 < 64*KLIN){
        int j = id2 & 7;
        int cell = id2 >> 3;
        int col = cell & 63;
        int sq = cell >> 6;
        int kl = sq*8 + j;
        int m = kl / 72, fp = kl - m*72;
        u16 v = 0;
        if (m < 5 && fp < 66){
            int of = (fp < 64) ? (fp + 2) : (fp - 64);
            float w;
            if (m == 0)      w = W_c[(of*5 + 0)*64 + col] - W_c[(of*5 + 2)*64 + col] - W_c[(of*5 + 4)*64 + col];
            else if (m == 2) w = 2.f * W_c[(of*5 + 2)*64 + col];
            else if (m == 4) w = 2.f * W_c[(of*5 + 4)*64 + col];
            else             w = W_c[(of*5 + m)*64 + col];
            v = (u16)f2bf(w);
        }
        Wt_c[id2] = v;
    }
}

// ---------------- build x0 (matrix 0), fp-major chunks, [state|inputs|pad] order ----------------
__global__ __launch_bounds__(256) void build_x0_k(const float* __restrict__ inputs,
                                                  const float* __restrict__ hx,
                                                  u16* __restrict__ Xu){
    __shared__ float sl[32*72];
    int n = blockIdx.x, t = threadIdx.x;
    #pragma unroll
    for (int i = 0; i < 8; ++i){
        int idx = t + i*256;                // 2048 hx elems -> fp 0..63
        int b = idx >> 6, f = idx & 63;
        sl[b*72 + f] = hx[b*HXROW + n*64 + f];
    }
    if (t < 64){
        int b = t >> 1, d = t & 1;
        sl[b*72 + 64 + d] = inputs[b*INROW + n*2 + d];
    }
    if (t < 192){
        int b = t / 6, k = t - b*6;
        sl[b*72 + 66 + k] = 0.f;
    }
    __syncthreads();
    #pragma unroll
    for (int i = 0; i < 2; ++i){
        int j = t + i*256;
        if (j < ROWCH){
            int b = j & 31, s = j >> 5;
            const float* p = &sl[b*72 + s*8];
            uint4 o;
            o.x = f2bf(p[0]) | (f2bf(p[1]) << 16);
            o.y = f2bf(p[2]) | (f2bf(p[3]) << 16);
            o.z = f2bf(p[4]) | (f2bf(p[5]) << 16);
            o.w = f2bf(p[6]) | (f2bf(p[7]) << 16);
            ((uint4*)Xu)[(size_t)n*NODECH + j] = o;
        }
    }
}

__device__ __forceinline__ void acc8(float* a, uint4 q, float v){
    a[0] += v*lo16(q.x); a[1] += v*hi16(q.x);
    a[2] += v*lo16(q.y); a[3] += v*hi16(q.y);
    a[4] += v*lo16(q.z); a[5] += v*hi16(q.z);
    a[6] += v*lo16(q.w); a[7] += v*hi16(q.w);
}
__device__ __forceinline__ uint4 pack8(const float* a){
    uint4 o;
    o.x = f2bf(a[0]) | (f2bf(a[1]) << 16);
    o.y = f2bf(a[2]) | (f2bf(a[3]) << 16);
    o.z = f2bf(a[4]) | (f2bf(a[5]) << 16);
    o.w = f2bf(a[6]) | (f2bf(a[7]) << 16);
    return o;
}

// ---------------- diffusion level 1: m1 = S0*m0, m3 = S1*m0 (one block per node) ----------------
__global__ __launch_bounds__(288) void diff1_k(u16* __restrict__ Xu,
                                               const int* __restrict__ rp,
                                               const int* __restrict__ c0, const float* __restrict__ v0,
                                               const int* __restrict__ c1, const float* __restrict__ v1){
    int t = threadIdx.x;
    if (t >= ROWCH) return;
    int n = blockIdx.x;
    const uint4* xb = (const uint4*)Xu;          // matrix 0 at offset 0
    float a[8] = {0,0,0,0,0,0,0,0};
    float d[8] = {0,0,0,0,0,0,0,0};
    // support 1: exactly 8 edges
    {
        uint4 q[8]; float vv[8];
        #pragma unroll
        for (int i = 0; i < 8; ++i){
            int c = c1[n*8 + i]; vv[i] = v1[n*8 + i];
            q[i] = xb[(size_t)c*NODECH + t];
        }
        #pragma unroll
        for (int i = 0; i < 8; ++i) acc8(d, q[i], vv[i]);
    }
    // support 0: CSR, variable degree
    int e = rp[n], end = rp[n+1];
    for (; e + 8 <= end; e += 8){
        uint4 q[8]; float vv[8];
        #pragma unroll
        for (int i = 0; i < 8; ++i){
            int c = c0[e+i]; vv[i] = v0[e+i];
            q[i] = xb[(size_t)c*NODECH + t];
        }
        #pragma unroll
        for (int i = 0; i < 8; ++i) acc8(a, q[i], vv[i]);
    }
    for (; e < end; ++e){
        int c = c0[e]; float v = v0[e];
        acc8(a, xb[(size_t)c*NODECH + t], v);
    }
    ((uint4*)Xu)[(size_t)n*NODECH + 1*ROWCH + t] = pack8(a);   // m=1: S0*x0
    ((uint4*)Xu)[(size_t)n*NODECH + 3*ROWCH + t] = pack8(d);   // m=3: S1*x0
}

// ---------------- diffusion level 2 (fold in W): m2 = S0*m1, m4 = S1*m3 ----------------
__global__ __launch_bounds__(288) void diff2_k(u16* __restrict__ Xu,
                                               const int* __restrict__ rp,
                                               const int* __restrict__ c0, const float* __restrict__ v0,
                                               const int* __restrict__ c1, const float* __restrict__ v1){
    int t = threadIdx.x;
    if (t >= ROWCH) return;
    int n = blockIdx.x;
    const uint4* xb = (const uint4*)Xu;
    float a[8] = {0,0,0,0,0,0,0,0};
    float d[8] = {0,0,0,0,0,0,0,0};
    {
        uint4 q[8]; float vv[8];
        #pragma unroll
        for (int i = 0; i < 8; ++i){
            int c = c1[n*8 + i]; vv[i] = v1[n*8 + i];
            q[i] = xb[(size_t)c*NODECH + 3*ROWCH + t];         // gather m=3
        }
        #pragma unroll
        for (int i = 0; i < 8; ++i) acc8(d, q[i], vv[i]);
    }
    int e = rp[n], end = rp[n+1];
    for (; e + 8 <= end; e += 8){
        uint4 q[8]; float vv[8];
        #pragma unroll
        for (int i = 0; i < 8; ++i){
            int c = c0[e+i]; vv[i] = v0[e+i];
            q[i] = xb[(size_t)c*NODECH + 1*ROWCH + t];         // gather m=1
        }
        #pragma unroll
        for (int i = 0; i < 8; ++i) acc8(a, q[i], vv[i]);
    }
    for (; e < end; ++e){
        int c = c0[e]; float v = v0[e];
        acc8(a, xb[(size_t)c*NODECH + 1*ROWCH + t], v);
    }
    ((uint4*)Xu)[(size_t)n*NODECH + 2*ROWCH + t] = pack8(a);   // m=2: S0^2*x0
    ((uint4*)Xu)[(size_t)n*NODECH + 4*ROWCH + t] = pack8(d);   // m=4: S1^2*x0
}

// ---------------- GEMM1: sigmoid(Xc@W_ru + b_ru); U out; X0.state <- r*hx ----------------
// SWAPPED OPERANDS: acc[mt][nt] = mfma(W_frag, X_frag, acc) -> D[wcol][b].
// Lane holds 4 CONSECUTIVE wcols (q*4+i within mt*16) for one b (nt*16+cIn):
// epilogue becomes 8B/16B vector accesses (VMEM-issue was the wall).
__global__ __launch_bounds__(1024) void gemm_ru_k(
        const u16* Xu,
        const u16* __restrict__ WtS,       // [(st*4+q)*128+col][8]
        const float* __restrict__ b_ru,
        u16* __restrict__ U, u16* X0st){
    __shared__ u16 Bs[24576];              // 48 KB = 6 steps
    __shared__ float biasL[128];
    const int t = threadIdx.x;
    const int lane = t & 63, w = t >> 6;
    const int node = blockIdx.x*16 + w;
    const int cIn = lane & 15, q = lane >> 4;
    const size_t noff = (size_t)node * NODEU16;
    const u16* Xn = Xu + noff;

    f32x4 acc[8][2];
    const f32x4 z4 = {0.f,0.f,0.f,0.f};
    #pragma unroll
    for (int mt = 0; mt < 8; ++mt)
        #pragma unroll
        for (int nt = 0; nt < 2; ++nt) acc[mt][nt] = z4;

    if (t < 128) biasL[t] = b_ru[t];
    // stage half 0 (steps 0..5): 3072 chunks, 3 per thread
    #pragma unroll
    for (int i = 0; i < 3; ++i)
        GLDS(WtS + (size_t)(i*1024 + t)*8, &Bs[(i*1024 + t)*8]);
    __syncthreads();

    #pragma unroll
    for (int h = 0; h < 2; ++h){
        if (h == 1){
            __syncthreads();
            #pragma unroll
            for (int i = 0; i < 3; ++i)
                GLDS(WtS + (size_t)(3072 + i*1024 + t)*8, &Bs[(i*1024 + t)*8]);
            __syncthreads();
        }
        #pragma unroll
        for (int ls = 0; ls < 6; ++ls){
            const int st = h*6 + ls;
            bf16x8 A0 = *(const bf16x8*)&Xn[(size_t)((st*4 + q)*32 + cIn)*8];
            bf16x8 A1 = *(const bf16x8*)&Xn[(size_t)((st*4 + q)*32 + 16 + cIn)*8];
            bf16x8 cb[8];
            #pragma unroll
            for (int mt = 0; mt < 8; ++mt)
                cb[mt] = *(const bf16x8*)&Bs[((ls*4 + q)*128 + mt*16 + cIn)*8];
            #pragma unroll
            for (int mt = 0; mt < 8; ++mt){
                acc[mt][0] = __builtin_amdgcn_mfma_f32_16x16x32_bf16(cb[mt], A0, acc[mt][0], 0,0,0);
                acc[mt][1] = __builtin_amdgcn_mfma_f32_16x16x32_bf16(cb[mt], A1, acc[mt][1], 0,0,0);
            }
        }
    }

    // epilogue: lane holds wcol = mt*16 + q*4 + i, b = nt*16 + cIn
    #pragma unroll
    for (int mt = 0; mt < 8; ++mt){
        const int wc0 = mt*16 + q*4;
        f32x4 b4 = *(const f32x4*)&biasL[wc0];
        #pragma unroll
        for (int nt = 0; nt < 2; ++nt){
            const int b = nt*16 + cIn;
            f32x4 d = acc[mt][nt];
            if (mt < 4){
                // r-gate RMW on state fp = wcol (slice wc0>>3, 4 u16 in-slice, 8B aligned)
                size_t base = noff + (size_t)((wc0 >> 3)*32 + b)*8 + (wc0 & 7);
                uint2 hv = *(uint2*)&X0st[base];
                float r0 = sigm(d[0] + b4.x), r1 = sigm(d[1] + b4.y);
                float r2 = sigm(d[2] + b4.z), r3 = sigm(d[3] + b4.w);
                uint2 o;
                o.x = f2bf(r0*lo16(hv.x)) | (f2bf(r1*hi16(hv.x)) << 16);
                o.y = f2bf(r2*lo16(hv.y)) | (f2bf(r3*hi16(hv.y)) << 16);
                *(uint2*)&X0st[base] = o;
            } else {
                float u0 = sigm(d[0] + b4.x), u1 = sigm(d[1] + b4.y);
                float u2 = sigm(d[2] + b4.z), u3 = sigm(d[3] + b4.w);
                uint2 o;
                o.x = f2bf(u0) | (f2bf(u1) << 16);
                o.y = f2bf(u2) | (f2bf(u3) << 16);
                *(uint2*)&U[(size_t)node*2048 + b*64 + (wc0 - 64)] = o;   // U[b][col]
            }
        }
    }
}

// ---------------- GEMM2: c = tanh(Xc@W_c + b_c); out = u*hx + (1-u)*c ----------------
// Swapped operands; U read as [b][col]; hx/out accessed as f32x4 (16B).
__global__ __launch_bounds__(1024) void gemm_c_k(
        const u16* __restrict__ Xu,
        const u16* __restrict__ WtS,       // [(st*4+q)*64+col][8]
        const float* __restrict__ b_c, const float* __restrict__ hx,
        const u16* __restrict__ U, float* __restrict__ out){
    __shared__ u16 Bs[24576];              // 48 KB = all 12 steps
    __shared__ float biasL[64];
    const int t = threadIdx.x;
    const int lane = t & 63, w = t >> 6;
    const int node = blockIdx.x*16 + w;
    const int cIn = lane & 15, q = lane >> 4;
    const size_t noff = (size_t)node * NODEU16;
    const u16* Xn = Xu + noff;

    f32x4 acc[4][2];
    const f32x4 z4 = {0.f,0.f,0.f,0.f};
    #pragma unroll
    for (int mt = 0; mt < 4; ++mt)
        #pragma unroll
        for (int nt = 0; nt < 2; ++nt) acc[mt][nt] = z4;

    if (t < 64) biasL[t] = b_c[t];
    // stage all of W_c: 3072 chunks, 3 per thread
    #pragma unroll
    for (int i = 0; i < 3; ++i)
        GLDS(WtS + (size_t)(i*1024 + t)*8, &Bs[(i*1024 + t)*8]);
    __syncthreads();

    #pragma unroll
    for (int st = 0; st < NSTEPS; ++st){
        bf16x8 A0 = *(const bf16x8*)&Xn[(size_t)((st*4 + q)*32 + cIn)*8];
        bf16x8 A1 = *(const bf16x8*)&Xn[(size_t)((st*4 + q)*32 + 16 + cIn)*8];
        bf16x8 cb[4];
        #pragma unroll
        for (int mt = 0; mt < 4; ++mt)
            cb[mt] = *(const bf16x8*)&Bs[((st*4 + q)*64 + mt*16 + cIn)*8];
        #pragma unroll
        for (int mt = 0; mt < 4; ++mt){
            acc[mt][0] = __builtin_amdgcn_mfma_f32_16x16x32_bf16(cb[mt], A0, acc[mt][0], 0,0,0);
            acc[mt][1] = __builtin_amdgcn_mfma_f32_16x16x32_bf16(cb[mt], A1, acc[mt][1], 0,0,0);
        }
    }

    // epilogue: wcol = mt*16 + q*4 + i, b = nt*16 + cIn
    #pragma unroll
    for (int mt = 0; mt < 4; ++mt){
        const int wc0 = mt*16 + q*4;
        f32x4 b4 = *(const f32x4*)&biasL[wc0];
        #pragma unroll
        for (int nt = 0; nt < 2; ++nt){
            const int b = nt*16 + cIn;
            f32x4 d = acc[mt][nt];
            uint2 up = *(const uint2*)&U[(size_t)node*2048 + b*64 + wc0];   // U[b][col]
            float u0 = lo16(up.x), u1 = hi16(up.x), u2 = lo16(up.y), u3 = hi16(up.y);
            const size_t gi = (size_t)b*HXROW + node*64 + wc0;
            f32x4 h4 = *(const f32x4*)&hx[gi];
            f32x4 o;
            o.x = u0*h4.x + (1.f - u0)*tanhf(d[0] + b4.x);
            o.y = u1*h4.y + (1.f - u1)*tanhf(d[1] + b4.y);
            o.z = u2*h4.z + (1.f - u2)*tanhf(d[2] + b4.z);
            o.w = u3*h4.w + (1.f - u3)*tanhf(d[3] + b4.w);
            *(f32x4*)&out[gi] = o;
        }
    }
}

// ---------------- launch ----------------
extern "C" void kernel_launch(void* const* d_in, const int* in_sizes, int n_in,
                              void* d_out, int out_size, void* d_ws, size_t ws_size,
                              hipStream_t stream){
    const float* inputs = (const float*)d_in[0];
    const float* hx     = (const float*)d_in[1];
    const float* W_ru   = (const float*)d_in[2];
    const float* b_ru   = (const float*)d_in[3];
    const float* W_c    = (const float*)d_in[4];
    const float* b_c    = (const float*)d_in[5];
    const int*   s0r    = (const int*)d_in[6];
    const int*   s0c    = (const int*)d_in[7];
    const float* s0v    = (const float*)d_in[8];
    const int*   s1c    = (const int*)d_in[10];
    const float* s1v    = (const float*)d_in[11];
    float* out = (float*)d_out;

    char* ws = (char*)d_ws;
    size_t off = 0;
    auto alloc = [&](size_t bytes) -> char* {
        char* p = ws + off;
        off += (bytes + 255) & ~(size_t)255;
        return p;
    };
    const size_t XU_BYTES = (size_t)NNODES * NODEU16 * 2;
    u16* Xu   = (u16*)alloc(XU_BYTES + 4096);      // +guard for k-tail overread of last node
    u16* U    = (u16*)alloc((size_t)NNODES*2048*2);
    u16* WtRU = (u16*)alloc((size_t)128*KLIN*2);   // 12 steps * 4096 u16
    u16* WtC  = (u16*)alloc((size_t)64*KLIN*2);    // 12 steps * 2048 u16
    int* counts  = (int*)alloc((size_t)NNODES*4);
    int* row_ptr = (int*)alloc((size_t)(NNODES+1)*4);
    int* cursor  = (int*)alloc((size_t)NNODES*4);
    int*   cols_s = (int*)alloc((size_t)EDG*4);
    float* vals_s = (float*)alloc((size_t)EDG*4);
    (void)ws_size; (void)in_sizes; (void)n_in; (void)out_size;

    // CSR build for support 0 + zero the tail guard
    hipMemsetAsync(counts, 0, (size_t)NNODES*4, stream);
    hipMemsetAsync((char*)Xu + XU_BYTES, 0, 4096, stream);
    hist_k<<<250, 256, 0, stream>>>(s0r, counts);
    scan_k<<<1, 256, 0, stream>>>(counts, row_ptr, cursor);
    scatter_k<<<250, 256, 0, stream>>>(s0r, s0c, s0v, cursor, cols_s, vals_s);

    prep_w_k<<<288, 256, 0, stream>>>(W_ru, W_c, WtRU, WtC);
    build_x0_k<<<NNODES, 256, 0, stream>>>(inputs, hx, Xu);

    // gconv 1 diffusion
    diff1_k<<<NNODES, 288, 0, stream>>>(Xu, row_ptr, cols_s, vals_s, s1c, s1v);
    diff2_k<<<NNODES, 288, 0, stream>>>(Xu, row_ptr, cols_s, vals_s, s1c, s1v);

    // GEMM1 + sigmoid; writes U and X0.state = r*hx
    gemm_ru_k<<<NNODES/16, 1024, 0, stream>>>(Xu, WtRU, b_ru, U, Xu);

    // gconv 2 diffusion (matrix 0 now holds [r*hx | inputs])
    diff1_k<<<NNODES, 288, 0, stream>>>(Xu, row_ptr, cols_s, vals_s, s1c, s1v);
    diff2_k<<<NNODES, 288, 0, stream>>>(Xu, row_ptr, cols_s, vals_s, s1c, s1v);

    // GEMM2 + tanh + final gate
    gemm_c_k<<<NNODES/16, 1024, 0, stream>>>(Xu, WtC, b_c, hx, U, out);
}